// Round 8
// baseline (752.457 us; speedup 1.0000x reference)
//
#include <hip/hip_runtime.h>
#include <stdint.h>

// Viterbi CRF decode: B=1024, T=1024, N=34 (32 tags + START=32 + END=33)
// Round-0 step structure (34j x 4h k-split, LDS ping-pong, lgkm-only
// barrier) with NB=2 batches PER THREAD: two independent batch chains
// interleaved in the instruction stream between barriers. Rounds 0-7
// showed wave-level overlap saturates (~1060cy/step, VALUBusy ~50%);
// in-stream ILP fills the dependency/latency stalls at issue time.
// Grid 512 -> 2 blocks/CU on top for cross-block barrier overlap.
#define BB 1024
#define TT 1024
#define NN 34
#define NP 36            // padded state dim in LDS score buffers
#define NB 2             // batches per thread (in-stream ILP)
#define TPB 136          // 34 j x 4 h
#define NEGV -6969.0f
#define PADV -1.0e30f

template<int C>
__device__ __forceinline__ int dpp_i(int x) {
    return __builtin_amdgcn_update_dpp(0, x, C, 0xF, 0xF, true);
}
template<int C>
__device__ __forceinline__ float dpp_f(float x) {
    return __int_as_float(dpp_i<C>(__float_as_int(x)));
}

// Barrier that drains LDS (lgkmcnt) only: global prefetch loads stay in
// flight across steps (plain __syncthreads would force vmcnt(0) -> exposes
// full HBM latency on the critical path every step).
__device__ __forceinline__ void lds_barrier() {
    asm volatile("s_waitcnt lgkmcnt(0)\n\ts_barrier" ::: "memory");
}

__global__ __launch_bounds__(TPB, 2) void viterbi_full(
        const float* __restrict__ feat,   // [B,T,34]
        const float* __restrict__ trans,  // [34,34]
        unsigned char* __restrict__ bpg,  // workspace [B,T,34] backpointers
        float* __restrict__ out)          // best[B] ++ path[B,T+1]
{
    __shared__ float sbuf[2][NB][NP];     // ping-pong score buffers
    __shared__ float fsb[NB][NN];
    __shared__ unsigned char Fm[NB][16][NN];
    __shared__ int Eb[NB][16];
    __shared__ int idxs[NB];

    const int r   = threadIdx.x;
    const int j   = r >> 2;          // 0..33 target state
    const int h   = r & 3;           // k-quarter; quads aligned (136%4==0)
    const int k0  = h * 9;
    const int bg0 = blockIdx.x * NB;

    // ---- init LDS score buffers (pads -1e30; init scores: START=0, else NEG)
    for (int e = r; e < 2 * NB * NP; e += TPB) {
        int kk = e % NP;
        ((float*)sbuf)[e] = (kk >= NN) ? PADV : ((kk == 32) ? 0.0f : NEGV);
    }

    // ---- per-thread constants in registers (shared across both batches)
    float tr[9];
    int   kreg[9];
#pragma unroll
    for (int i = 0; i < 9; ++i) {
        int k = k0 + i;
        tr[i]   = (k < NN) ? trans[j * NN + k] : 0.0f;
        kreg[i] = k;
    }
    const float trE = (r < NN) ? trans[33 * NN + r] : 0.0f;

    const float* fpb[NB];
    unsigned char* bptb[NB];
#pragma unroll
    for (int b = 0; b < NB; ++b) {
        fpb[b]  = feat + (size_t)(bg0 + b) * TT * NN + j;
        bptb[b] = bpg  + (size_t)(bg0 + b) * TT * NN + j;
    }

    // 4-deep feature prefetch ring per batch (t = 0..3)
    float fr0[NB], fr1[NB], fr2[NB], fr3[NB];
#pragma unroll
    for (int b = 0; b < NB; ++b) {
        fr0[b] = fpb[b][0 * NN]; fr1[b] = fpb[b][1 * NN];
        fr2[b] = fpb[b][2 * NN]; fr3[b] = fpb[b][3 * NN];
    }

    __syncthreads();

    // one Viterbi step for BOTH batches between barriers. Exact fp order
    // (s+f)+t per batch (identical to the verified single-batch kernel);
    // argmax = first index attaining max (tree max + eq-scan + min-index).
    // SRD/SWR are ping-pong indices; FRQ is this slot's feature ring.
#define VSTEP(SRD, SWR, FRQ, QOFF, PF)                                        \
    {                                                                         \
        float fv_[NB];                                                        \
        _Pragma("unroll") for (int b = 0; b < NB; ++b) {                      \
            fv_[b] = FRQ[b];                                                  \
            if (PF) FRQ[b] = fpb[b][(4 + QOFF) * NN];                         \
        }                                                                     \
        float vv_[NB][9];                                                     \
        _Pragma("unroll") for (int b = 0; b < NB; ++b) {                      \
            const float* srd_ = &sbuf[SRD][b][0];                            \
            _Pragma("unroll") for (int i = 0; i < 9; ++i)                     \
                vv_[b][i] = (srd_[k0 + i] + fv_[b]) + tr[i];                  \
        }                                                                     \
        _Pragma("unroll") for (int b = 0; b < NB; ++b) {                      \
            float m_ = fmaxf(fmaxf(fmaxf(vv_[b][0], vv_[b][1]),               \
                                   fmaxf(vv_[b][2], vv_[b][3])),              \
                             fmaxf(fmaxf(vv_[b][4], vv_[b][5]),               \
                                   fmaxf(vv_[b][6], vv_[b][7])));             \
            m_ = fmaxf(m_, vv_[b][8]);                                        \
            m_ = fmaxf(m_, dpp_f<0xB1>(m_));   /* quad xor 1 */               \
            m_ = fmaxf(m_, dpp_f<0x4E>(m_));   /* quad xor 2 */               \
            int am_ = 127;                                                    \
            _Pragma("unroll") for (int i = 8; i >= 0; --i)                    \
                am_ = (vv_[b][i] == m_) ? kreg[i] : am_;                      \
            int ao_ = dpp_i<0xB1>(am_); am_ = (ao_ < am_) ? ao_ : am_;        \
            ao_ = dpp_i<0x4E>(am_);     am_ = (ao_ < am_) ? ao_ : am_;        \
            if (h == 0) { sbuf[SWR][b][j] = m_;                               \
                          bptb[b][QOFF * NN] = (unsigned char)am_; }          \
        }                                                                     \
        lds_barrier();                                                        \
    }

    // ---- forward: 255 iters x 4 steps (prefetch t+4) + 4-step epilogue
    for (int n = 0; n < 255; ++n) {
        VSTEP(0, 1, fr0, 0, true)
        VSTEP(1, 0, fr1, 1, true)
        VSTEP(0, 1, fr2, 2, true)
        VSTEP(1, 0, fr3, 3, true)
#pragma unroll
        for (int b = 0; b < NB; ++b) { fpb[b] += 4 * NN; bptb[b] += 4 * NN; }
    }
    VSTEP(0, 1, fr0, 0, false)
    VSTEP(1, 0, fr1, 1, false)
    VSTEP(0, 1, fr2, 2, false)
    VSTEP(1, 0, fr3, 3, false)
    // final scores (t=1024 even) live in sbuf[0]

    // ---- end transition + final argmax (one thread per batch)
#pragma unroll
    for (int b = 0; b < NB; ++b)
        if (r < NN) fsb[b][r] = sbuf[0][b][r] + trE;
    __syncthreads();   // also drains vmcnt: all bp stores of all waves done
    if (r < NB) {
        const int b = r;
        float bm = fsb[b][0]; int bi = 0;
        for (int k = 1; k < NN; ++k) {
            float v = fsb[b][k];
            if (v > bm) { bm = v; bi = k; }
        }
        out[bg0 + b] = bm; idxs[b] = bi;
    }
    __syncthreads();

    // ---- backtrack on this block's own bp (L2-resident, same CU/XCD)
    // level-1: 16 chunks x 64 steps x 34 hypotheses per batch;
    // 136 thr x (4 chunks x NB batches) interleaved chases (ILP)
    {
        int g = (r >= 102) ? 3 : ((r >= 68) ? 2 : ((r >= 34) ? 1 : 0));
        int x = r - 34 * g;
        int mv[NB][4];
#pragma unroll
        for (int b = 0; b < NB; ++b)
#pragma unroll
            for (int cc = 0; cc < 4; ++cc) mv[b][cc] = x;
        for (int i = 63; i >= 0; --i) {
#pragma unroll
            for (int b = 0; b < NB; ++b) {
                const unsigned char* bbb = bpg + (size_t)(bg0 + b) * TT * NN;
#pragma unroll
                for (int cc = 0; cc < 4; ++cc) {
                    int c = g + 4 * cc;
                    mv[b][cc] = bbb[(size_t)((c * 64 + i) * NN) + mv[b][cc]];
                }
            }
        }
#pragma unroll
        for (int b = 0; b < NB; ++b)
#pragma unroll
            for (int cc = 0; cc < 4; ++cc) Fm[b][g + 4 * cc][x] = mv[b][cc];
    }
    __syncthreads();

    // level-2: serial 16-chunk scan (one thread per batch)
    if (r < NB) {
        const int b = r;
        int e = idxs[b];
        Eb[b][15] = e;
        for (int c = 15; c >= 1; --c) { e = Fm[b][c][e]; Eb[b][c - 1] = e; }
    }
    __syncthreads();

    // emit: winning hypothesis per chunk re-chases and writes the path
    if (r < 16 * NB) {
        const int b = r >> 4, c = r & 15;
        const unsigned char* bbb = bpg + (size_t)(bg0 + b) * TT * NN;
        float* po = out + BB + (size_t)(bg0 + b) * (TT + 1);
        int m = Eb[b][c];
        for (int i = 63; i >= 0; --i) {
            m = bbb[(size_t)((c * 64 + i) * NN) + m];
            po[c * 64 + i] = (float)m;
        }
    }
    if (r >= 16 * NB && r < 16 * NB + NB) {
        const int b = r - 16 * NB;
        (out + BB + (size_t)(bg0 + b) * (TT + 1))[TT] = (float)idxs[b];
    }
}

extern "C" void kernel_launch(void* const* d_in, const int* in_sizes, int n_in,
                              void* d_out, int out_size, void* d_ws, size_t ws_size,
                              hipStream_t stream) {
    const float* feat  = (const float*)d_in[0];   // [1024,1024,34]
    const float* trans = (const float*)d_in[1];   // [34,34]
    float* out = (float*)d_out;                   // 1024 + 1024*1025 floats
    unsigned char* bp = (unsigned char*)d_ws;     // 35,651,584 B backpointers

    viterbi_full<<<BB / NB, TPB, 0, stream>>>(feat, trans, bp, out);
}

// Round 9
// 622.385 us; speedup vs baseline: 1.2090x; 1.2090x over previous
//
#include <hip/hip_runtime.h>
#include <stdint.h>

// Viterbi CRF decode: B=1024, T=1024, N=34 (32 tags + START=32 + END=33)
// One wave per batch, one wave per 64-thread block (grid 1024 = 1 wave/SIMD).
// lane j = target state (j<34 active). Scores broadcast via per-block LDS.
// Forward recursion has NO barriers: same-wave DS ops are pipe-ordered.
// All forward-pass LDS ops are inline-asm volatile:
//   write m -> issue 9 broadcast reads -> (argmax eq-scan + bp store run in
//   the LDS latency shadow) -> s_waitcnt lgkmcnt(0) -> next step's adds.
//
// ldspad[9000] (36 KB static LDS): caps the COMPILER'S occupancy estimate at
// 4 workgroups/CU = 1 wave/EU, which flips the pre-RA scheduler's register-
// pressure budget to the full 512-VGPR file. Rounds 2/3/5/6 all failed
// because the default 8-wave pressure target (VGPR pinned at 52-64) demoted
// the 34-reg transition row -> re-fetched from memory EVERY serial step.
// Runtime cost: zero (grid 1024 = 4 blocks/CU fits exactly at <=40960 B).
#define BB 1024
#define TT 1024
#define NN 34
#define NEGV -6969.0f

typedef float v2f __attribute__((ext_vector_type(2)));
typedef float v4f __attribute__((ext_vector_type(4)));

__device__ __forceinline__ float fmax3(float a, float b, float c) {
    return fmaxf(fmaxf(a, b), c);   // fuses to v_max3_f32
}
__device__ __forceinline__ int imin2(int a, int b) { return a < b ? a : b; }
__device__ __forceinline__ int imin3(int a, int b, int c) {
    return imin2(imin2(a, b), c);   // fuses to v_min3_i32
}

__global__ __launch_bounds__(64) void viterbi_wave(
        const float* __restrict__ feat,   // [B,T,34]
        const float* __restrict__ trans,  // [34,34]
        unsigned char* __restrict__ bpg,  // workspace [B,T,34] backpointers
        float* __restrict__ out)          // best[B] ++ path[B,T+1]
{
    __shared__ __align__(16) float scW[64];   // score broadcast (this wave)
    __shared__ unsigned char Fm[16][NN];      // backtrack level-1 results
    __shared__ int Eb[16];                    // backtrack level-2 carries
    __shared__ float ldspad[9000];            // occupancy-target cap (see top)

    const int lane = threadIdx.x & 63;
    const int j    = lane;                    // target state
    const int jm   = (j < NN) ? j : (NN - 1); // clamp for idle lanes
    const bool act = (j < NN);
    const int bg   = blockIdx.x;

    ldspad[lane] = 0.0f;                      // keep the pad allocated

    // ---- per-lane constants: transitions row j (34 floats, packed)
    v4f t4[8]; v2f t2;
    {
        const float* trow = trans + jm * NN;
#pragma unroll
        for (int i = 0; i < 8; ++i)
            t4[i] = (v4f){trow[4*i], trow[4*i+1], trow[4*i+2], trow[4*i+3]};
        t2 = (v2f){trow[32], trow[33]};
    }

    const float* fp = feat + (size_t)bg * TT * NN + jm;
    unsigned char* bpt = bpg + (size_t)bg * TT * NN + lane;

    // LDS byte addresses (low 32 bits of the generic address = LDS offset)
    const uint32_t lbase = (uint32_t)(uintptr_t)(&scW[0]);
    const uint32_t lwr   = lbase + ((uint32_t)lane << 2);

    // broadcast score registers (asm outputs -> cannot be sunk/remat'd)
    v4f q0, q1, q2, q3, q4, q5, q6, q7; v2f q8v;

#define RD_ALL()                                                              \
    asm volatile("ds_read_b128 %0, %1 offset:0"   : "=v"(q0)  : "v"(lbase)); \
    asm volatile("ds_read_b128 %0, %1 offset:16"  : "=v"(q1)  : "v"(lbase)); \
    asm volatile("ds_read_b128 %0, %1 offset:32"  : "=v"(q2)  : "v"(lbase)); \
    asm volatile("ds_read_b128 %0, %1 offset:48"  : "=v"(q3)  : "v"(lbase)); \
    asm volatile("ds_read_b128 %0, %1 offset:64"  : "=v"(q4)  : "v"(lbase)); \
    asm volatile("ds_read_b128 %0, %1 offset:80"  : "=v"(q5)  : "v"(lbase)); \
    asm volatile("ds_read_b128 %0, %1 offset:96"  : "=v"(q6)  : "v"(lbase)); \
    asm volatile("ds_read_b128 %0, %1 offset:112" : "=v"(q7)  : "v"(lbase)); \
    asm volatile("ds_read_b64  %0, %1 offset:128" : "=v"(q8v) : "v"(lbase))

    // ---- init scores (lane k holds score[k]); lanes>=34 junk, never read
    {
        float iv = (lane == 32) ? 0.0f : NEGV;
        asm volatile("ds_write_b32 %0, %1" :: "v"(lwr), "v"(iv));
        RD_ALL();
        asm volatile("s_waitcnt lgkmcnt(0)" ::: "memory");
        __builtin_amdgcn_sched_barrier(0);
    }

    // 4-deep feature prefetch ring (t = 0..3)
    float fr0 = fp[0*NN], fr1 = fp[1*NN], fr2 = fp[2*NN], fr3 = fp[3*NN];

    // one Viterbi step. exact fp order (s+f)+tr; argmax = first index at max.
    auto vstep = [&](float fv, unsigned char* bpw) {
        const v4f f4 = (v4f){fv, fv, fv, fv};
        const v2f f2 = (v2f){fv, fv};
        v4f w0 = (q0 + f4) + t4[0];   // v_pk_add_f32 pairs
        v4f w1 = (q1 + f4) + t4[1];
        v4f w2 = (q2 + f4) + t4[2];
        v4f w3 = (q3 + f4) + t4[3];
        v4f w4 = (q4 + f4) + t4[4];
        v4f w5 = (q5 + f4) + t4[5];
        v4f w6 = (q6 + f4) + t4[6];
        v4f w7 = (q7 + f4) + t4[7];
        v2f w8 = (q8v + f2) + t2;
        float wv[NN];
#define UNP(i, W) wv[4*(i)+0]=(W).x; wv[4*(i)+1]=(W).y; \
                  wv[4*(i)+2]=(W).z; wv[4*(i)+3]=(W).w;
        UNP(0, w0) UNP(1, w1) UNP(2, w2) UNP(3, w3)
        UNP(4, w4) UNP(5, w5) UNP(6, w6) UNP(7, w7)
#undef UNP
        wv[32] = w8.x; wv[33] = w8.y;
        float a[12];
#pragma unroll
        for (int i = 0; i < 11; ++i) a[i] = fmax3(wv[3*i], wv[3*i+1], wv[3*i+2]);
        a[11] = wv[33];
        float b0 = fmax3(a[0], a[1], a[2]), b1 = fmax3(a[3], a[4], a[5]);
        float b2 = fmax3(a[6], a[7], a[8]), b3 = fmax3(a[9], a[10], a[11]);
        float m = fmaxf(fmaxf(b0, b1), fmaxf(b2, b3));
        // publish score[j], then issue refill reads (DS pipe is in-order)
        asm volatile("ds_write_b32 %0, %1" :: "v"(lwr), "v"(m));
        RD_ALL();
        // ---- LDS latency shadow: argmax eq-TREE + bp store
        int e[NN];
#pragma unroll
        for (int k = 0; k < NN; ++k) e[k] = (wv[k] == m) ? k : 127;
        int r[12];
#pragma unroll
        for (int i = 0; i < 11; ++i) r[i] = imin3(e[3*i], e[3*i+1], e[3*i+2]);
        r[11] = e[33];
        int s0 = imin3(r[0], r[1], r[2]),  s1 = imin3(r[3], r[4], r[5]);
        int s2 = imin3(r[6], r[7], r[8]),  s3 = imin3(r[9], r[10], r[11]);
        int am = imin2(imin2(s0, s1), imin2(s2, s3));
        if (act) *bpw = (unsigned char)am;
        // ---- end shadow; wait for reads, fence both ways (rule #18)
        __builtin_amdgcn_sched_barrier(0);
        asm volatile("s_waitcnt lgkmcnt(0)" ::: "memory");
        __builtin_amdgcn_sched_barrier(0);
    };

    // ---- forward: 255 iters x 4 steps (prefetch t+4) + 4-step epilogue
    for (int n = 0; n < 255; ++n) {
        { float f = fr0; fr0 = fp[4*NN]; vstep(f, bpt + 0*NN); }
        { float f = fr1; fr1 = fp[5*NN]; vstep(f, bpt + 1*NN); }
        { float f = fr2; fr2 = fp[6*NN]; vstep(f, bpt + 2*NN); }
        { float f = fr3; fr3 = fp[7*NN]; vstep(f, bpt + 3*NN); }
        fp += 4*NN; bpt += 4*NN;
    }
    vstep(fr0, bpt + 0*NN);
    vstep(fr1, bpt + 1*NN);
    vstep(fr2, bpt + 2*NN);
    vstep(fr3, bpt + 3*NN);
    // q0..q8v hold the broadcast of final scores (t=1024) in every lane.

    // ---- end transition + final argmax (redundant in all lanes, no LDS)
    int bi;
    float bm;
    {
        const float* er = trans + (NN - 1) * NN;   // uniform -> s_loads
        float qv[NN];
#define UNQ(i, W) qv[4*(i)+0]=(W).x; qv[4*(i)+1]=(W).y; \
                  qv[4*(i)+2]=(W).z; qv[4*(i)+3]=(W).w;
        UNQ(0, q0) UNQ(1, q1) UNQ(2, q2) UNQ(3, q3)
        UNQ(4, q4) UNQ(5, q5) UNQ(6, q6) UNQ(7, q7)
#undef UNQ
        qv[32] = q8v.x; qv[33] = q8v.y;
        float wv[NN];
#pragma unroll
        for (int k = 0; k < NN; ++k) wv[k] = qv[k] + er[k];
        float a[12];
#pragma unroll
        for (int i = 0; i < 11; ++i) a[i] = fmax3(wv[3*i], wv[3*i+1], wv[3*i+2]);
        a[11] = wv[33];
        float b0 = fmax3(a[0], a[1], a[2]), b1 = fmax3(a[3], a[4], a[5]);
        float b2 = fmax3(a[6], a[7], a[8]), b3 = fmax3(a[9], a[10], a[11]);
        bm = fmaxf(fmaxf(b0, b1), fmaxf(b2, b3));
        int e[NN];
#pragma unroll
        for (int k = 0; k < NN; ++k) e[k] = (wv[k] == bm) ? k : 127;
        int r[12];
#pragma unroll
        for (int i = 0; i < 11; ++i) r[i] = imin3(e[3*i], e[3*i+1], e[3*i+2]);
        r[11] = e[33];
        int s0 = imin3(r[0], r[1], r[2]),  s1 = imin3(r[3], r[4], r[5]);
        int s2 = imin3(r[6], r[7], r[8]),  s3 = imin3(r[9], r[10], r[11]);
        bi = imin2(imin2(s0, s1), imin2(s2, s3));
    }
    if (lane == 0) out[bg] = bm;

    // ---- backtrack on this wave's own bp (stores by this wave; L2-resident)
    asm volatile("s_waitcnt vmcnt(0)" ::: "memory");
    const unsigned char* __restrict__ bb = bpg + (size_t)bg * TT * NN;

    // level-1: 16 chunks x 64 steps x 34 hypotheses; lane (c=lane>>2, sub),
    // 9 interleaved chases per lane (ILP hides L2 latency)
    {
        const int c = lane >> 2;
        const int sub = lane & 3;
        int mv[9];
#pragma unroll
        for (int qi = 0; qi < 9; ++qi) {
            int x = sub + 4 * qi;
            mv[qi] = (x < NN) ? x : (NN - 1);
        }
        const unsigned char* cb = bb + (size_t)c * 64 * NN;
        for (int i = 63; i >= 0; --i) {
            const unsigned char* rb = cb + (size_t)i * NN;
#pragma unroll
            for (int qi = 0; qi < 9; ++qi) mv[qi] = rb[mv[qi]];
        }
#pragma unroll
        for (int qi = 0; qi < 9; ++qi) {
            int x = sub + 4 * qi;
            if (x < NN) Fm[c][x] = (unsigned char)mv[qi];
        }
    }

    // level-2: serial 16-chunk scan (same-wave in-order DS, no barrier)
    if (lane == 0) {
        int e = bi;
        Eb[15] = e;
        for (int c = 15; c >= 1; --c) { e = Fm[c][e]; Eb[c - 1] = e; }
    }

    // emit: winning hypothesis per chunk re-chases and writes the path
    float* po = out + BB + (size_t)bg * (TT + 1);
    if (lane < 16) {
        int c = lane;
        int m = Eb[c];
        for (int i = 63; i >= 0; --i) {
            m = bb[(size_t)((c * 64 + i) * NN) + m];
            po[c * 64 + i] = (float)m;
        }
    }
    if (lane == 16) po[TT] = (float)bi;
}

extern "C" void kernel_launch(void* const* d_in, const int* in_sizes, int n_in,
                              void* d_out, int out_size, void* d_ws, size_t ws_size,
                              hipStream_t stream) {
    const float* feat  = (const float*)d_in[0];   // [1024,1024,34]
    const float* trans = (const float*)d_in[1];   // [34,34]
    float* out = (float*)d_out;                   // 1024 + 1024*1025 floats
    unsigned char* bp = (unsigned char*)d_ws;     // 35,651,584 B backpointers

    viterbi_wave<<<BB, 64, 0, stream>>>(feat, trans, bp, out);
}